// Round 2
// baseline (276.968 us; speedup 1.0000x reference)
//
#include <hip/hip_runtime.h>
#include <math.h>

#define HH 1536
#define WW 1536
#define HWSZ (HH*WW)

__global__ __launch_bounds__(256) void step_kernel(
    const float* __restrict__ phi,
    const float* __restrict__ sensory,
    const float* __restrict__ gamma,
    const float* __restrict__ alpha,
    const float* __restrict__ mixw,
    float* __restrict__ out,
    float* __restrict__ sums)
{
    __shared__ float s_mix[100];
    __shared__ float s_g[10];
    __shared__ float s_a0;
    const int tid = threadIdx.x;
    if (tid < 100) s_mix[tid] = mixw[tid];
    if (tid < 10)  s_g[tid]   = gamma[tid];
    if (tid == 0)  s_a0       = alpha[0];
    __syncthreads();

    const int x = blockIdx.x * 256 + tid;
    const int y = blockIdx.y;

    const int xm1 = (x == 0)      ? WW - 1     : x - 1;
    const int xp1 = (x == WW - 1) ? 0          : x + 1;
    const int xm2 = (x < 2)       ? x + WW - 2 : x - 2;
    const int xp2 = (x >= WW - 2) ? x - WW + 2 : x + 2;
    const int ym1 = (y == 0)      ? HH - 1     : y - 1;
    const int yp1 = (y == HH - 1) ? 0          : y + 1;
    const int ym2 = (y < 2)       ? y + HH - 2 : y - 2;
    const int yp2 = (y >= HH - 2) ? y - HH + 2 : y + 2;

    const int r0  = y   * WW;
    const int rm1 = ym1 * WW;
    const int rp1 = yp1 * WW;
    const int rm2 = ym2 * WW;
    const int rp2 = yp2 * WW;

    float p[10], lap[10], bl[10];
    #pragma unroll
    for (int c = 0; c < 10; ++c) {
        const float* pc = phi + (size_t)c * HWSZ;
        const float c0 = pc[r0 + x];
        const float nn = pc[rm1 + x];
        const float ss = pc[rp1 + x];
        const float wv = pc[r0 + xm1];
        const float ee = pc[r0 + xp1];
        const float s1 = nn + ss + wv + ee;
        p[c]   = c0;
        lap[c] = s1 - 4.0f * c0;
        if (c == 0 || c == 3 || c == 4 || c == 9) {
            const float d1 = pc[rm1 + xm1];
            const float d2 = pc[rm1 + xp1];
            const float d3 = pc[rp1 + xm1];
            const float d4 = pc[rp1 + xp1];
            const float t1 = pc[rm2 + x];
            const float t2 = pc[rp2 + x];
            const float t3 = pc[r0 + xm2];
            const float t4 = pc[r0 + xp2];
            bl[c] = 20.0f * c0 - 8.0f * s1 + 2.0f * (d1 + d2 + d3 + d4) + (t1 + t2 + t3 + t4);
        } else {
            bl[c] = 0.0f;
        }
    }

    float d[10];
    {
        const float p0 = p[0];
        d[0] = -s_g[0]*lap[0] - s_a0*p0*p0*p0 + 0.12f*bl[0];
        const float p1 = p[1];
        d[1] = -s_g[1]*lap[1] + 0.15f*sinf(p1) + 0.08f*p1*p1*p1;
        const float p2 = p[2];
        d[2] = -s_g[2]*lap[2] + 0.2f*p2*(1.0f - p2*p2);
        const float p3 = p[3];
        const float p3_2 = p3*p3;
        d[3] = -s_g[3]*lap[3] - 0.03f*p3_2*p3_2*p3 + 0.08f*bl[3];
        const float p4 = p[4];
        d[4] = -s_g[4]*lap[4] + 0.12f*p4*logf(fabsf(p4) + 1e-6f) + 0.02f*bl[4];
        const float p5 = p[5];
        const float p5_2 = p5*p5;
        d[5] = -s_g[5]*lap[5] + 0.08f*p5_2*p5 - 0.02f*p5_2*p5_2*p5;
        const float p6 = p[6];
        const float p6_2 = p6*p6;
        d[6] = -s_g[6]*lap[6] + 0.06f*p6_2*p6_2 - 0.04f*p6;
        const float p7 = fminf(fmaxf(p[7], -2.0f), 2.0f);
        d[7] = -s_g[7]*lap[7] + 0.08f*sinhf(p7);
        const float p8 = p[8];
        d[8] = -s_g[8]*lap[8] + 0.05f*p8*p8 - 0.08f*p8;
        const float p9 = p[9];
        const float p9_2 = p9*p9;
        const float p9_3 = p9_2*p9;
        d[9] = -s_g[9]*lap[9] + 0.02f*p9_3*p9_3 - 0.04f*p9_3 + 0.01f*bl[9];
    }

    const float fm = (p[0] + p[1] + p[2] + p[3] + p[4]) * 0.2f;
    const float sm = (p[5] + p[6] + p[7] + p[8] + p[9]) * 0.2f;
    const float sd = sensory[r0 + x];

    float pn[10];
    #pragma unroll
    for (int o = 0; o < 10; ++o) {
        float cp = 0.0f;
        #pragma unroll
        for (int c = 0; c < 10; ++c) cp = fmaf(s_mix[o*10 + c], p[c], cp);
        float dd = d[o];
        if (o < 5) {
            dd += 0.06f * cp + 0.02f * sm;           // EPS_FAST, S2F
            if (o == 0) dd += 0.2f  * sd;
            if (o == 4) dd += 0.08f * fabsf(sd);
            pn[o] = p[o] + 0.02f * dd;               // DT * FAST_DT
        } else {
            dd += 0.02f * cp + 0.04f * fm;           // EPS_SLOW, F2S
            if (o == 9) dd += 0.05f * sd;
            pn[o] = p[o] + 0.004f * dd;              // DT * SLOW_DT
        }
        pn[o] = fminf(fmaxf(pn[o], -4.0f), 4.0f);
        out[(size_t)o * HWSZ + r0 + x] = pn[o];
    }

    // Block-level reduction of per-channel sums of phi_next, then 10 atomics.
    const int lane = tid & 63;
    const int wave = tid >> 6;
    __shared__ float s_red[4][10];
    #pragma unroll
    for (int c = 0; c < 10; ++c) {
        float v = pn[c];
        #pragma unroll
        for (int off = 32; off > 0; off >>= 1) v += __shfl_down(v, off, 64);
        if (lane == 0) s_red[wave][c] = v;
    }
    __syncthreads();
    if (tid < 10) {
        const float v = s_red[0][tid] + s_red[1][tid] + s_red[2][tid] + s_red[3][tid];
        atomicAdd(&sums[tid], v);
    }
}

__global__ void finalize_kernel(const float* __restrict__ sums,
                                float* __restrict__ out)
{
    const int t = threadIdx.x;
    const float inv = 1.0f / (float)HWSZ;
    const size_t base = (size_t)10 * HWSZ;
    if (t == 0) out[base]     = sums[0] * inv;  // phi1_mean (channel 0)
    if (t == 1) out[base + 1] = sums[4] * inv;  // phi5_mean (channel 4)
    if (t >= 2 && t < 12) out[base + 2 + (t - 2)] = sums[t - 2] * inv;  // field_means
}

extern "C" void kernel_launch(void* const* d_in, const int* in_sizes, int n_in,
                              void* d_out, int out_size, void* d_ws, size_t ws_size,
                              hipStream_t stream) {
    const float* phi     = (const float*)d_in[0];
    const float* sensory = (const float*)d_in[1];
    const float* gamma   = (const float*)d_in[2];
    const float* alpha   = (const float*)d_in[3];
    const float* mixw    = (const float*)d_in[4];
    float* out = (float*)d_out;
    float* sums = (float*)d_ws;

    hipMemsetAsync(sums, 0, 10 * sizeof(float), stream);

    dim3 grid(WW / 256, HH);
    step_kernel<<<grid, 256, 0, stream>>>(phi, sensory, gamma, alpha, mixw, out, sums);
    finalize_kernel<<<1, 64, 0, stream>>>(sums, out);
}

// Round 3
// 240.243 us; speedup vs baseline: 1.1529x; 1.1529x over previous
//
#include <hip/hip_runtime.h>
#include <math.h>

#define HH 1536
#define WW 1536
#define HWSZ (HH*WW)
#define NT 384   // one row per block: 384 threads x 4 px = 1536

__device__ __forceinline__ float4 LD4(const float* __restrict__ p, int row, int t) {
    return reinterpret_cast<const float4*>(p + row)[t];
}

__global__ __launch_bounds__(NT) void step_kernel(
    const float* __restrict__ phi,
    const float* __restrict__ sensory,
    const float* __restrict__ gamma,
    const float* __restrict__ alpha,
    const float* __restrict__ mixw,
    float* __restrict__ out,
    float* __restrict__ sums)
{
    __shared__ float s_mix[100];
    __shared__ float s_g[10];
    __shared__ float s_a0;
    __shared__ float s_red[6][10];

    const int tid = threadIdx.x;
    if (tid < 100) s_mix[tid] = mixw[tid];
    if (tid < 10)  s_g[tid]   = gamma[tid];
    if (tid == 0)  s_a0       = alpha[0];
    __syncthreads();

    // XCD-banded swizzle: blocks dispatch round-robin over 8 XCDs; give each
    // XCD a contiguous 192-row band so stencil row-reuse hits its own L2.
    const int blk = blockIdx.x;
    const int y = (blk & 7) * 192 + (blk >> 3);

    const int x0 = tid * 4;

    const int ym1 = (y == 0)      ? HH - 1     : y - 1;
    const int yp1 = (y == HH - 1) ? 0          : y + 1;
    const int ym2 = (y < 2)       ? y + HH - 2 : y - 2;
    const int yp2 = (y >= HH - 2) ? y - HH + 2 : y + 2;

    const int r0  = y   * WW;
    const int rm1 = ym1 * WW;
    const int rp1 = yp1 * WW;
    const int rm2 = ym2 * WW;
    const int rp2 = yp2 * WW;

    // x halo indices (x0 is a multiple of 4, so x0==0 is the only left wrap)
    const int xl1 = (x0 == 0)        ? WW - 1 : x0 - 1;
    const int xl2 = (x0 == 0)        ? WW - 2 : x0 - 2;
    const int xr1 = (x0 + 4 == WW)   ? 0      : x0 + 4;
    const int xr2 = (x0 + 4 == WW)   ? 1      : x0 + 5;

    float pv[10][4];   // phi values (kept for coupling)
    float dv[10][4];   // per-channel dphi (nonlinear + lap/bilap part)

    #pragma unroll
    for (int c = 0; c < 10; ++c) {
        const float* pc = phi + (size_t)c * HWSZ;
        const float4 cm = LD4(pc, r0,  tid);
        const float4 nn = LD4(pc, rm1, tid);
        const float4 ss = LD4(pc, rp1, tid);
        const float wl1 = pc[r0 + xl1];
        const float wr1 = pc[r0 + xr1];

        float lap[4];
        lap[0] = nn.x + ss.x + wl1  + cm.y - 4.0f * cm.x;
        lap[1] = nn.y + ss.y + cm.x + cm.z - 4.0f * cm.y;
        lap[2] = nn.z + ss.z + cm.y + cm.w - 4.0f * cm.z;
        lap[3] = nn.w + ss.w + cm.z + wr1  - 4.0f * cm.w;

        float bl[4] = {0.f, 0.f, 0.f, 0.f};
        if (c == 0 || c == 3 || c == 4 || c == 9) {
            // direct 13-pt bilaplacian: 20c -8(N+S+W+E) +2(diag) + (NN+SS+WW+EE)
            const float4 t2n = LD4(pc, rm2, tid);
            const float4 t2s = LD4(pc, rp2, tid);
            const float wl2 = pc[r0  + xl2];
            const float wr2 = pc[r0  + xr2];
            const float nwl = pc[rm1 + xl1];
            const float ner = pc[rm1 + xr1];
            const float swl = pc[rp1 + xl1];
            const float ser = pc[rp1 + xr1];
            bl[0] = 20.0f*cm.x - 8.0f*(nn.x + ss.x + wl1  + cm.y)
                  + 2.0f*(nwl  + nn.y + swl  + ss.y) + (t2n.x + t2s.x + wl2  + cm.z);
            bl[1] = 20.0f*cm.y - 8.0f*(nn.y + ss.y + cm.x + cm.z)
                  + 2.0f*(nn.x + nn.z + ss.x + ss.z) + (t2n.y + t2s.y + wl1  + cm.w);
            bl[2] = 20.0f*cm.z - 8.0f*(nn.z + ss.z + cm.y + cm.w)
                  + 2.0f*(nn.y + nn.w + ss.y + ss.w) + (t2n.z + t2s.z + cm.x + wr1);
            bl[3] = 20.0f*cm.w - 8.0f*(nn.w + ss.w + cm.z + wr1)
                  + 2.0f*(nn.z + ner  + ss.z + ser ) + (t2n.w + t2s.w + cm.y + wr2);
        }

        pv[c][0] = cm.x; pv[c][1] = cm.y; pv[c][2] = cm.z; pv[c][3] = cm.w;

        #pragma unroll
        for (int k = 0; k < 4; ++k) {
            const float pp = pv[c][k];
            const float lv = lap[k];
            const float bv = bl[k];
            float dd;
            switch (c) {
            case 0: dd = -s_g[0]*lv - s_a0*pp*pp*pp + 0.12f*bv; break;
            case 1: dd = -s_g[1]*lv + 0.15f*sinf(pp) + 0.08f*pp*pp*pp; break;
            case 2: dd = -s_g[2]*lv + 0.2f*pp*(1.0f - pp*pp); break;
            case 3: { const float p2 = pp*pp;
                      dd = -s_g[3]*lv - 0.03f*p2*p2*pp + 0.08f*bv; } break;
            case 4: dd = -s_g[4]*lv + 0.12f*pp*logf(fabsf(pp) + 1e-6f) + 0.02f*bv; break;
            case 5: { const float p2 = pp*pp;
                      dd = -s_g[5]*lv + 0.08f*p2*pp - 0.02f*p2*p2*pp; } break;
            case 6: { const float p2 = pp*pp;
                      dd = -s_g[6]*lv + 0.06f*p2*p2 - 0.04f*pp; } break;
            case 7: { const float pc7 = fminf(fmaxf(pp, -2.0f), 2.0f);
                      dd = -s_g[7]*lv + 0.08f*sinhf(pc7); } break;
            case 8: dd = -s_g[8]*lv + 0.05f*pp*pp - 0.08f*pp; break;
            default: { const float p3 = pp*pp*pp;
                       dd = -s_g[9]*lv + 0.02f*p3*p3 - 0.04f*p3 + 0.01f*bv; } break;
            }
            dv[c][k] = dd;
        }
    }

    float fmv[4], smv[4], sdk[4];
    {
        const float4 sd4 = LD4(sensory, r0, tid);
        sdk[0] = sd4.x; sdk[1] = sd4.y; sdk[2] = sd4.z; sdk[3] = sd4.w;
        #pragma unroll
        for (int k = 0; k < 4; ++k) {
            fmv[k] = (pv[0][k] + pv[1][k] + pv[2][k] + pv[3][k] + pv[4][k]) * 0.2f;
            smv[k] = (pv[5][k] + pv[6][k] + pv[7][k] + pv[8][k] + pv[9][k]) * 0.2f;
        }
    }

    const int lane = tid & 63;
    const int wave = tid >> 6;

    #pragma unroll
    for (int o = 0; o < 10; ++o) {
        float pn[4];
        #pragma unroll
        for (int k = 0; k < 4; ++k) {
            float cp = 0.0f;
            #pragma unroll
            for (int c = 0; c < 10; ++c) cp = fmaf(s_mix[o*10 + c], pv[c][k], cp);
            float dd = dv[o][k];
            if (o < 5) {
                dd += 0.06f * cp + 0.02f * smv[k];          // EPS_FAST, S2F
                if (o == 0) dd += 0.2f  * sdk[k];
                if (o == 4) dd += 0.08f * fabsf(sdk[k]);
                pn[k] = pv[o][k] + 0.02f * dd;              // DT * FAST_DT
            } else {
                dd += 0.02f * cp + 0.04f * fmv[k];          // EPS_SLOW, F2S
                if (o == 9) dd += 0.05f * sdk[k];
                pn[k] = pv[o][k] + 0.004f * dd;             // DT * SLOW_DT
            }
            pn[k] = fminf(fmaxf(pn[k], -4.0f), 4.0f);
        }
        float4 o4; o4.x = pn[0]; o4.y = pn[1]; o4.z = pn[2]; o4.w = pn[3];
        reinterpret_cast<float4*>(out + (size_t)o * HWSZ + r0)[tid] = o4;

        float s = pn[0] + pn[1] + pn[2] + pn[3];
        #pragma unroll
        for (int off = 32; off > 0; off >>= 1) s += __shfl_down(s, off, 64);
        if (lane == 0) s_red[wave][o] = s;
    }

    __syncthreads();
    if (tid < 10) {
        float v = 0.0f;
        #pragma unroll
        for (int w = 0; w < 6; ++w) v += s_red[w][tid];
        atomicAdd(&sums[tid], v);
    }
}

__global__ void finalize_kernel(const float* __restrict__ sums,
                                float* __restrict__ out)
{
    const int t = threadIdx.x;
    const float inv = 1.0f / (float)HWSZ;
    const size_t base = (size_t)10 * HWSZ;
    if (t == 0) out[base]     = sums[0] * inv;  // phi1_mean (channel 0)
    if (t == 1) out[base + 1] = sums[4] * inv;  // phi5_mean (channel 4)
    if (t >= 2 && t < 12) out[base + 2 + (t - 2)] = sums[t - 2] * inv;  // field_means
}

extern "C" void kernel_launch(void* const* d_in, const int* in_sizes, int n_in,
                              void* d_out, int out_size, void* d_ws, size_t ws_size,
                              hipStream_t stream) {
    const float* phi     = (const float*)d_in[0];
    const float* sensory = (const float*)d_in[1];
    const float* gamma   = (const float*)d_in[2];
    const float* alpha   = (const float*)d_in[3];
    const float* mixw    = (const float*)d_in[4];
    float* out = (float*)d_out;
    float* sums = (float*)d_ws;

    hipMemsetAsync(sums, 0, 10 * sizeof(float), stream);

    step_kernel<<<dim3(HH), NT, 0, stream>>>(phi, sensory, gamma, alpha, mixw, out, sums);
    finalize_kernel<<<1, 64, 0, stream>>>(sums, out);
}